// Round 4
// baseline (948.228 us; speedup 1.0000x reference)
//
#include <hip/hip_runtime.h>
#include <hip/hip_bf16.h>
#include <cstdint>
#include <cstddef>

// Problem constants (fixed by setup_inputs)
#define NB   32
#define NPOS 3136      // 56*56
#define NC   384
#define NHD  8
#define DH   48
#define NAG  16
#define MROWS (NB*NPOS)   // 100352
#define CQK  768

static constexpr float kScale = 0.14433756729740643f;   // 48^-0.5
static constexpr float kInv196 = 1.0f / 196.0f;

typedef __bf16 bf16x8 __attribute__((ext_vector_type(8)));
typedef float  f32x4  __attribute__((ext_vector_type(4)));

// async global->LDS, 16B per lane (wave-uniform LDS base + lane*16 dest)
__device__ static inline void async_copy16(void* lds, const void* g) {
    __builtin_amdgcn_global_load_lds(
        (const __attribute__((address_space(1))) unsigned int*)g,
        (__attribute__((address_space(3))) unsigned int*)lds, 16, 0, 0);
}

// ---------------- setup: weight cvt fp32->bf16 + zero pool accumulator ----------------
__global__ __launch_bounds__(256) void setup_kernel(
    const float* __restrict__ Wq, const float* __restrict__ Wkv,
    const float* __restrict__ Wp,
    __hip_bfloat16* __restrict__ wqkb, __hip_bfloat16* __restrict__ wpb,
    float* __restrict__ agqk)
{
    const int bid = blockIdx.x, t = threadIdx.x;
    if (bid < 432) {
        const float* src; __hip_bfloat16* dst; int lb = bid;
        if (lb < 144)      { src = Wq;  dst = wqkb; }
        else if (lb < 288) { src = Wkv; dst = wqkb + 147456; lb -= 144; }
        else               { src = Wp;  dst = wpb;           lb -= 288; }
        int i = lb * 256 + t;     // < 36864
        float4 v = ((const float4*)src)[i];
        union { ushort4 u; __hip_bfloat16 h[4]; } p;
        p.h[0] = __float2bfloat16(v.x);
        p.h[1] = __float2bfloat16(v.y);
        p.h[2] = __float2bfloat16(v.z);
        p.h[3] = __float2bfloat16(v.w);
        ((ushort4*)dst)[i] = p.u;
    } else {
        int i = (bid - 432) * 256 + t;   // < 98304 (= 393216 floats / 4)
        float4 z; z.x = z.y = z.z = z.w = 0.f;
        ((float4*)agqk)[i] = z;
    }
}

// ---------------- bf16 MFMA GEMM: C[M][Nn] = A[M][K] * B[Nn][K]^T (+bias) -------------
// 128x128 tile, BK=64, 256 threads (4 waves, 2x2 of 64x64).
// A_F32: A is fp32, reg-staged + converted + swizzled ds_write (fused cvt).
// POOL:  epilogue accumulates 14x14 block sums into poolbuf [32][16][768] via atomics.
// Bijective XCD swizzle (m204) so blocks sharing an A-panel colocate on one XCD L2.
template<bool HAS_BIAS, bool OUT_BF16, bool A_F32, bool POOL>
__global__ __launch_bounds__(256) void gemm_kernel(
    const void* __restrict__ Ap,
    const __hip_bfloat16* __restrict__ Bw,
    const float* __restrict__ bias,
    void* __restrict__ Cout,
    float* __restrict__ poolbuf,
    int nBlkN, int Nn, int K)
{
    __shared__ unsigned char smem[32768];
    unsigned char* smA = smem;            // [128 rows][128 B]
    unsigned char* smB = smem + 16384;

    const int t = threadIdx.x;
    // bijective XCD swizzle: orig -> (xcd, idx) -> contiguous chunk per XCD
    const int nwg = gridDim.x;
    const int qq = nwg >> 3, rr = nwg & 7;
    const int xcd = blockIdx.x & 7, sidx0 = blockIdx.x >> 3;
    const int wgid = (xcd < rr ? xcd * (qq + 1) : rr * (qq + 1) + (xcd - rr) * qq) + sidx0;
    const int m0 = (wgid / nBlkN) * 128;
    const int n0 = (wgid % nBlkN) * 128;

    const int lane = t & 63;
    const int w    = t >> 6;
    const int wm   = (w >> 1) * 64;
    const int wn   = (w & 1) * 64;
    const int lr   = lane & 15;
    const int lg   = lane >> 4;

    // bf16 async staging (A when !A_F32; B always)
    const int Kb    = K << 1;                       // bf16 row bytes
    const int lrow  = lane >> 3;                    // 0..7
    const int lslot = ((lane & 7) ^ lrow) << 4;     // swizzled source byte-in-128B
    const char* Ag = A_F32 ? nullptr
                   : (const char*)Ap + (size_t)(m0 + 32 * w + lrow) * Kb + lslot;
    const char* Bg = (const char*)Bw + (size_t)(n0 + 32 * w + lrow) * Kb + lslot;
    unsigned char* ldsA = smA + w * 4096;
    unsigned char* ldsB = smB + w * 4096;

    // fp32 A staging: thread t -> row ar, col-half ah (32 floats = 128 B source)
    const int ar = t >> 1, ah = t & 1;
    const float* Af = A_F32 ? (const float*)Ap + (size_t)(m0 + ar) * K + ah * 32 : nullptr;

    f32x4 acc[4][4] = {};

    const int nk = K >> 6;
    for (int kt = 0; kt < nk; ++kt) {
        float4 af[8];
        if (A_F32) {
            const float4* s4 = (const float4*)(Af + kt * 64);
            #pragma unroll
            for (int j = 0; j < 8; ++j) af[j] = s4[j];
        }
        __syncthreads();    // previous tile fully consumed
        if (A_F32) {
            union { bf16x8 v[4]; __hip_bfloat16 h[32]; } cv;
            #pragma unroll
            for (int j = 0; j < 8; ++j) {
                cv.h[4 * j + 0] = __float2bfloat16(af[j].x);
                cv.h[4 * j + 1] = __float2bfloat16(af[j].y);
                cv.h[4 * j + 2] = __float2bfloat16(af[j].z);
                cv.h[4 * j + 3] = __float2bfloat16(af[j].w);
            }
            #pragma unroll
            for (int qc = 0; qc < 4; ++qc) {
                int sl = (((ah << 2) | qc) ^ (ar & 7)) << 4;
                *(bf16x8*)(smA + ar * 128 + sl) = cv.v[qc];
            }
            #pragma unroll
            for (int j = 0; j < 4; ++j)
                async_copy16(ldsB + j * 1024, Bg + (size_t)(8 * j) * Kb);
            Bg += 128;
        } else {
            #pragma unroll
            for (int j = 0; j < 4; ++j) {
                async_copy16(ldsA + j * 1024, Ag + (size_t)(8 * j) * Kb);
                async_copy16(ldsB + j * 1024, Bg + (size_t)(8 * j) * Kb);
            }
            Ag += 128; Bg += 128;
        }
        __syncthreads();    // drains vmcnt+lgkm -> tile ready

        #pragma unroll
        for (int kk = 0; kk < 2; ++kk) {
            bf16x8 av[4], bv[4];
            #pragma unroll
            for (int mf = 0; mf < 4; ++mf) {
                const int row = wm + mf * 16 + lr;
                av[mf] = *(const bf16x8*)(smA + row * 128 + ((((kk << 2) | lg) ^ (row & 7)) << 4));
            }
            #pragma unroll
            for (int nf = 0; nf < 4; ++nf) {
                const int row = wn + nf * 16 + lr;
                bv[nf] = *(const bf16x8*)(smB + row * 128 + ((((kk << 2) | lg) ^ (row & 7)) << 4));
            }
            #pragma unroll
            for (int mf = 0; mf < 4; ++mf)
                #pragma unroll
                for (int nf = 0; nf < 4; ++nf)
                    acc[mf][nf] = __builtin_amdgcn_mfma_f32_16x16x32_bf16(av[mf], bv[nf], acc[mf][nf], 0, 0, 0);
        }
    }

    // C write. C/D layout: col=lane&15, row=(lane>>4)*4+j   [verified mapping]
    #pragma unroll
    for (int mf = 0; mf < 4; ++mf) {
        #pragma unroll
        for (int nf = 0; nf < 4; ++nf) {
            #pragma unroll
            for (int j = 0; j < 4; ++j) {
                int row = m0 + wm + mf * 16 + (lg << 2) + j;
                int col = n0 + wn + nf * 16 + lr;
                float v = acc[mf][nf][j];
                if (HAS_BIAS) v += bias[col];
                if (OUT_BF16)
                    ((__hip_bfloat16*)Cout)[(size_t)row * Nn + col] = __float2bfloat16(v);
                else
                    ((float*)Cout)[(size_t)row * Nn + col] = v;
            }
        }
    }

    if (POOL) {
        // 128-row tile crosses at most one 784-row (b,py) boundary -> 2 slots.
        __syncthreads();    // all LDS fragment reads done; reuse smem
        float (*ps)[4][128] = (float (*)[4][128])smem;   // [slot][px][col] = 4 KB
        for (int i = t; i < 1024; i += 256) ((float*)ps)[i] = 0.f;
        __syncthreads();
        const int base784 = m0 / 784;
        #pragma unroll
        for (int mf = 0; mf < 4; ++mf) {
            #pragma unroll
            for (int nf = 0; nf < 4; ++nf) {
                #pragma unroll
                for (int j = 0; j < 4; ++j) {
                    int r  = m0 + wm + mf * 16 + (lg << 2) + j;
                    int s  = (r / 784) - base784;            // 0 or 1
                    int px = (r % 56) / 14;
                    int cl = wn + nf * 16 + lr;
                    atomicAdd(&ps[s][px][cl], acc[mf][nf][j]);   // ds_add_f32
                }
            }
        }
        __syncthreads();
        for (int i = t; i < 1024; i += 256) {
            int s = i >> 9, px = (i >> 7) & 3, cl = i & 127;
            int r784 = base784 + s;
            if (r784 < 128) {
                int b = r784 >> 2, py = r784 & 3;
                atomicAdd(&poolbuf[(size_t)(b * NAG + py * 4 + px) * CQK + n0 + cl],
                          ps[s][px][cl]);
            }
        }
    }
}

// ---------------- agent gating + agent_new GEMM, one block per batch ----------------
// agqk holds UN-normalized pooled sums; /196 applied here.
__global__ __launch_bounds__(256) void agent_fused_kernel(
    const float* __restrict__ agqk,          // [32][16][768] sums
    const float* __restrict__ w_g,           // [384]
    const __hip_bfloat16* __restrict__ wpb,  // [384][384] bf16
    const float* __restrict__ bp,            // [384]
    __hip_bfloat16* __restrict__ anb,        // [32][16][384] agent_new
    __hip_bfloat16* __restrict__ akb)        // [32][16][384] agent_k
{
    __shared__ float aq[NAG][NC];                  // 24 KB
    __shared__ __hip_bfloat16 gks[NAG][NC + 8];    // 12.5 KB (pad 16B vs bank stride)
    __shared__ float Av[NAG];
    __shared__ float G[NC];
    const int b = blockIdx.x, t = threadIdx.x;
    const float* base = agqk + (size_t)b * NAG * CQK;

    for (int i = t; i < NAG * NC; i += 256) {
        int a = i / NC, cc = i - a * NC;
        aq[a][cc] = base[a * CQK + cc] * kInv196;
    }
    __syncthreads();

    {   // gate A[a] = scale * dot(aq[a], w_g) — 16 threads per agent
        int a = t >> 4, l = t & 15;
        float s = 0.f;
        for (int cc = l; cc < NC; cc += 16) s += aq[a][cc] * w_g[cc];
        s += __shfl_down(s, 8, 16);
        s += __shfl_down(s, 4, 16);
        s += __shfl_down(s, 2, 16);
        s += __shfl_down(s, 1, 16);
        if (l == 0) Av[a] = s * kScale;
    }
    __syncthreads();

    for (int cc = t; cc < NC; cc += 256) {   // G[c] = sum_a A[a]*aq[a][c]
        float s = 0.f;
        #pragma unroll
        for (int a = 0; a < NAG; ++a) s += Av[a] * aq[a][cc];
        G[cc] = s;
    }
    __syncthreads();

    for (int i = t; i < NAG * NC; i += 256) {
        int a = i / NC, cc = i - a * NC;
        float kv = base[a * CQK + NC + cc] * kInv196;
        akb[(size_t)b * NAG * NC + i] = __float2bfloat16(kv);
        gks[a][cc] = __float2bfloat16(G[cc] * kv);
    }
    __syncthreads();

    // MFMA: an = gk @ Wp^T. wave w -> cols 96w..96w+95 (6 frags), K=384 (12 steps)
    const int lane = t & 63, wv = t >> 6, lr = lane & 15, lg = lane >> 4;
    f32x4 acc[6] = {};
    for (int ks = 0; ks < 12; ++ks) {
        bf16x8 av = *(const bf16x8*)&gks[lr][ks * 32 + lg * 8];
        #pragma unroll
        for (int nf = 0; nf < 6; ++nf) {
            int ncol = wv * 96 + nf * 16 + lr;
            bf16x8 bv = *(const bf16x8*)(wpb + (size_t)ncol * NC + ks * 32 + lg * 8);
            acc[nf] = __builtin_amdgcn_mfma_f32_16x16x32_bf16(av, bv, acc[nf], 0, 0, 0);
        }
    }
    #pragma unroll
    for (int nf = 0; nf < 6; ++nf) {
        #pragma unroll
        for (int j = 0; j < 4; ++j) {
            int agent = (lg << 2) + j;           // C row
            int ncol  = wv * 96 + nf * 16 + lr;  // C col
            float v = acc[nf][j] + bp[ncol] + aq[agent][ncol];
            anb[((size_t)b * NAG + agent) * NC + ncol] = __float2bfloat16(v);
        }
    }
}

// ---------------- attention: softmax(q*scale @ an^T) @ ak, per (b,head) ----------------
__global__ __launch_bounds__(256) void attn_kernel(
    const __hip_bfloat16* __restrict__ qk,    // [B*NPOS][768], q = ch 0..383
    const __hip_bfloat16* __restrict__ anb,   // [B][16][384]
    const __hip_bfloat16* __restrict__ akb,   // [B][16][384]
    __hip_bfloat16* __restrict__ outb)        // [B*NPOS][384]
{
    const int bh = blockIdx.x;
    const int b = bh >> 3, hd = bh & 7;
    __shared__ float an_s[NAG][DH];
    __shared__ float ak_s[NAG][DH];
    const int t = threadIdx.x;
    for (int i = t; i < NAG * DH; i += 256) {
        int a = i / DH, dd = i - a * DH;
        an_s[a][dd] = (float)anb[((size_t)b * NAG + a) * NC + hd * DH + dd];
        ak_s[a][dd] = (float)akb[((size_t)b * NAG + a) * NC + hd * DH + dd];
    }
    __syncthreads();
    const int row = blockIdx.y * 256 + t;
    if (row >= NPOS) return;

    union { uint4 u[6]; __hip_bfloat16 h[48]; } qv;
    const uint4* qp = (const uint4*)(qk + ((size_t)b * NPOS + row) * CQK + hd * DH);
    #pragma unroll
    for (int i = 0; i < 6; ++i) qv.u[i] = qp[i];
    float qf[DH];
    #pragma unroll
    for (int dd = 0; dd < DH; ++dd) qf[dd] = (float)qv.h[dd];

    float sv[NAG];
    float mx = -1e30f;
    #pragma unroll
    for (int a = 0; a < NAG; ++a) {
        float s = 0.f;
        #pragma unroll
        for (int dd = 0; dd < DH; ++dd) s += qf[dd] * an_s[a][dd];
        s *= kScale;
        sv[a] = s;
        mx = fmaxf(mx, s);
    }
    float den = 0.f;
    #pragma unroll
    for (int a = 0; a < NAG; ++a) { sv[a] = __expf(sv[a] - mx); den += sv[a]; }
    const float inv = 1.f / den;

    float o[DH];
    #pragma unroll
    for (int dd = 0; dd < DH; ++dd) o[dd] = 0.f;
    #pragma unroll
    for (int a = 0; a < NAG; ++a) {
        float p = sv[a] * inv;
        #pragma unroll
        for (int dd = 0; dd < DH; ++dd) o[dd] += p * ak_s[a][dd];
    }

    union { uint4 u[6]; __hip_bfloat16 h[48]; } ov;
    #pragma unroll
    for (int dd = 0; dd < DH; ++dd) ov.h[dd] = __float2bfloat16(o[dd]);
    uint4* op = (uint4*)(outb + ((size_t)b * NPOS + row) * NC + hd * DH);
    #pragma unroll
    for (int i = 0; i < 6; ++i) op[i] = ov.u[i];
}

// ---------------- launch ----------------
extern "C" void kernel_launch(void* const* d_in, const int* in_sizes, int n_in,
                              void* d_out, int out_size, void* d_ws, size_t ws_size,
                              hipStream_t stream) {
    (void)in_sizes; (void)n_in; (void)out_size; (void)ws_size;
    const float* x   = (const float*)d_in[0];
    const float* Wq  = (const float*)d_in[3];
    const float* Wkv = (const float*)d_in[4];
    const float* wg  = (const float*)d_in[5];
    const float* Wp  = (const float*)d_in[6];
    const float* bp  = (const float*)d_in[7];
    float* out = (float*)d_out;

    // workspace layout (bytes)
    char* w = (char*)d_ws;
    __hip_bfloat16* aout = (__hip_bfloat16*)(w);                // 77,070,336  attn output bf16
    __hip_bfloat16* qkb  = (__hip_bfloat16*)(w + 77070336);     // 154,140,672 fused q|k bf16
    __hip_bfloat16* wqkb = (__hip_bfloat16*)(w + 231211008);    // 589,824     [Wq;Wkv] bf16
    __hip_bfloat16* wpb  = (__hip_bfloat16*)(w + 231800832);    // 294,912     Wp bf16
    float*          agqk = (float*)(w + 232095744);             // 1,572,864   pooled q|k sums fp32
    __hip_bfloat16* anb  = (__hip_bfloat16*)(w + 233668608);    // 393,216     agent_new bf16
    __hip_bfloat16* akb  = (__hip_bfloat16*)(w + 234061824);    // 393,216     agent_k bf16

    // 1. weight cvt + zero pool accumulator (one dispatch)
    setup_kernel<<<816, 256, 0, stream>>>(Wq, Wkv, Wp, wqkb, wpb, agqk);

    // 2. fused q|k GEMM (A fp32 in-kernel cvt) + pooling epilogue
    gemm_kernel<false, true, true, true><<<(MROWS / 128) * (CQK / 128), 256, 0, stream>>>(
        x, wqkb, nullptr, qkb, agqk, CQK / 128, CQK, NC);

    // 3. agent gating + agent_new MFMA (one block per batch)
    agent_fused_kernel<<<NB, 256, 0, stream>>>(agqk, wg, wpb, bp, anb, akb);

    // 4. attention -> bf16 aout
    attn_kernel<<<dim3(NB * NHD, (NPOS + 255) / 256), 256, 0, stream>>>(qkb, anb, akb, aout);

    // 5. final projection GEMM + bias -> fp32 d_out
    gemm_kernel<true, false, false, false><<<(MROWS / 128) * (NC / 128), 256, 0, stream>>>(
        aout, wpb, bp, out, nullptr, NC / 128, NC, NC);
}